// Round 11
// baseline (71.713 us; speedup 1.0000x reference)
//
#include <hip/hip_runtime.h>
#include <hip/hip_bf16.h>
#include <math.h>

#define N_FEAT 6272
#define DIM    128
#define M_BANK 30000
#define M_PAD  30080
#define NB     8
#define PH     28
#define PW     28
#define IMG    224
#define BM     256        // 4 waves x 64 rows (4 mb-blocks of 16)
#define BN     64         // bank cols per LDS tile (16KB)
#define TPT    10         // tiles per chunk: 470 tiles / 47 chunks
#define CHUNKS 47
#define TILE_BYTES 16384  // 16 slices x 64 cols x 16B

#define BANK_BLOCKS (M_PAD / 16)     // 1880
#define FEAT_BLOCKS (N_FEAT / 4)     // 1568

typedef __attribute__((ext_vector_type(8)))  __bf16 bf16x8_t;
typedef __attribute__((ext_vector_type(2)))  __bf16 bf16x2_t;
typedef __attribute__((ext_vector_type(4)))  float  f32x4_t;
typedef __attribute__((ext_vector_type(2)))  float  f32x2_t;

typedef const __attribute__((address_space(1))) unsigned int g_u32;
typedef __attribute__((address_space(3))) unsigned int l_u32;

// Fused prep: blocks [0,BANK_BLOCKS) retile bank fp32->bf16 (64-col tiles,
// byte addr = (r>>6)*16384 + s*1024 + (r&63)*16) + row sum-of-squares (+inf pad);
// blocks [BANK_BLOCKS, BANK_BLOCKS+FEAT_BLOCKS) do feature rows + nn init.
__global__ __launch_bounds__(256) void prep_all(const float* __restrict__ bank,
                                                const float* __restrict__ feat,
                                                unsigned char* __restrict__ mbt,
                                                float* __restrict__ m2,
                                                __bf16* __restrict__ fbb,
                                                float* __restrict__ f2,
                                                unsigned int* __restrict__ nn) {
    if (blockIdx.x < BANK_BLOCKS) {
        const int tid  = threadIdx.x;
        const int s    = tid & 15;          // k-slice
        const int rloc = tid >> 4;          // 16 rows per block
        const int r    = blockIdx.x * 16 + rloc;
        const bool valid = r < M_BANK;
        float x[8];
        if (valid) {
            f32x4_t v0 = *(const f32x4_t*)(bank + (size_t)r * DIM + s * 8);
            f32x4_t v1 = *(const f32x4_t*)(bank + (size_t)r * DIM + s * 8 + 4);
            x[0]=v0.x; x[1]=v0.y; x[2]=v0.z; x[3]=v0.w;
            x[4]=v1.x; x[5]=v1.y; x[6]=v1.z; x[7]=v1.w;
        } else {
            #pragma unroll
            for (int e = 0; e < 8; ++e) x[e] = 0.f;
        }
        float sum = 0.f;
        #pragma unroll
        for (int e = 0; e < 8; ++e) sum += x[e] * x[e];
        sum += __shfl_xor(sum, 1);
        sum += __shfl_xor(sum, 2);
        sum += __shfl_xor(sum, 4);
        sum += __shfl_xor(sum, 8);
        bf16x8_t p;
        #pragma unroll
        for (int e = 0; e < 8; ++e) p[e] = (__bf16)x[e];
        const size_t addr = (size_t)(r >> 6) * TILE_BYTES + s * 1024 + (r & 63) * 16;
        *(bf16x8_t*)(mbt + addr) = p;
        if (s == 0) m2[r] = valid ? sum : INFINITY;
        return;
    }
    int wave = ((blockIdx.x - BANK_BLOCKS) * blockDim.x + threadIdx.x) >> 6;
    int lane = threadIdx.x & 63;
    if (wave >= N_FEAT) return;
    f32x2_t v = *(const f32x2_t*)(feat + (size_t)wave * DIM + lane * 2);
    float s = v.x * v.x + v.y * v.y;
    #pragma unroll
    for (int m = 1; m < 64; m <<= 1) s += __shfl_xor(s, m);
    bf16x2_t p; p.x = (__bf16)v.x; p.y = (__bf16)v.y;
    *(bf16x2_t*)(fbb + (size_t)wave * DIM + lane * 2) = p;
    if (lane == 0) { f2[wave] = s; nn[wave] = 0x7f800000u; }
}

// Phase-interleaved dist+min (T3/T4-style on the r10 shape).
// Per 64-col tile, 4 phases: {ds_read b[4] for n | issue 1/4 of next tile's
// stage | s_barrier | setprio+16 MFMA | fold | s_barrier}. vmcnt(0) ONLY at
// the tile boundary, draining loads issued a full tile earlier (free).
// Raw barriers (no attached drain). m2 prefetched one tile ahead.
__global__ __launch_bounds__(256, 3) void dist_min_kernel(
        const __bf16* __restrict__ fbb, const unsigned char* __restrict__ mbt,
        const float* __restrict__ f2, const float* __restrict__ m2,
        unsigned int* __restrict__ nn) {
    __shared__ __align__(16) unsigned char lds[2 * TILE_BYTES];
    const int tid  = threadIdx.x;
    const int lane = tid & 63;
    const int w    = tid >> 6;
    const int c16  = lane & 15;   // A-row16 / B-col16 / C-col
    const int kq   = lane >> 4;   // k-quarter (8 elems each)
    const int arow = blockIdx.x * BM + w * 64;

    // A fragments: afrag[mb][kk] = A[arow+mb*16+c16][kk*32 + kq*8 .. +7]
    bf16x8_t afrag[4][4];
    #pragma unroll
    for (int mb = 0; mb < 4; ++mb) {
        int row = arow + mb * 16 + c16;
        if (row >= N_FEAT) row = N_FEAT - 1;   // tail clamp (results discarded)
        #pragma unroll
        for (int kk = 0; kk < 4; ++kk)
            afrag[mb][kk] = *(const bf16x8_t*)(fbb + (size_t)row * DIM + kk * 32 + kq * 8);
    }

    float rmin[4][4];
    #pragma unroll
    for (int mb = 0; mb < 4; ++mb)
        #pragma unroll
        for (int j = 0; j < 4; ++j) rmin[mb][j] = INFINITY;

    const int tile0 = blockIdx.y * TPT;

#define STAGE1(tile_idx, bufsel, i_)                                                  \
    {   const unsigned char* sp_ = mbt + (size_t)(tile_idx) * TILE_BYTES + tid * 16;  \
        unsigned char* dp_ = lds + (bufsel) * TILE_BYTES + tid * 16;                  \
        __builtin_amdgcn_global_load_lds((g_u32*)(sp_ + (i_) * 4096),                 \
                                         (l_u32*)(dp_ + (i_) * 4096), 16, 0, 0); }

    // prologue: m2 for tile0, stage tile0 fully -> buf0, drain, barrier.
    float m2cur[4];
    #pragma unroll
    for (int n = 0; n < 4; ++n) m2cur[n] = m2[tile0 * BN + n * 16 + c16];
    #pragma unroll
    for (int i = 0; i < 4; ++i) STAGE1(tile0, 0, i);
    asm volatile("s_waitcnt vmcnt(0)" ::: "memory");
    __builtin_amdgcn_s_barrier();

    int cur = 0;
    #pragma unroll 1
    for (int t = 0; t < TPT; ++t) {
        const unsigned char* buf = lds + cur * TILE_BYTES;
        float m2next[4];
        #pragma unroll
        for (int n = 0; n < 4; ++n) {
            // phase n: ds_read this n's B fragments
            bf16x8_t b[4];
            #pragma unroll
            for (int kk = 0; kk < 4; ++kk)
                b[kk] = *(const bf16x8_t*)(buf + (kk * 4 + kq) * 1024 + (n * 16 + c16) * 16);
            // issue 1/4 of next tile's stage (stays in flight across barriers)
            if (t + 1 < TPT) {
                STAGE1(tile0 + t + 1, cur ^ 1, n);
                if (n == 0) {
                    #pragma unroll
                    for (int q = 0; q < 4; ++q)
                        m2next[q] = m2[(tile0 + t + 1) * BN + q * 16 + c16];
                }
            }
            __builtin_amdgcn_s_barrier();
            f32x4_t acc[4];
            __builtin_amdgcn_s_setprio(1);
            #pragma unroll
            for (int mb = 0; mb < 4; ++mb) {
                acc[mb] = (f32x4_t){0.f, 0.f, 0.f, 0.f};
                #pragma unroll
                for (int kk = 0; kk < 4; ++kk)
                    acc[mb] = __builtin_amdgcn_mfma_f32_16x16x32_bf16(afrag[mb][kk], b[kk],
                                                                      acc[mb], 0, 0, 0);
            }
            __builtin_amdgcn_s_setprio(0);
            #pragma unroll
            for (int mb = 0; mb < 4; ++mb)
                #pragma unroll
                for (int j = 0; j < 4; ++j)
                    rmin[mb][j] = fminf(rmin[mb][j], fmaf(-2.f, acc[mb][j], m2cur[n]));
            __builtin_amdgcn_s_barrier();
        }
        // tile boundary: next tile's stage loads were issued >= 1 phase-cycle
        // ago; drain (free) and publish the buffer swap.
        if (t + 1 < TPT) {
            asm volatile("s_waitcnt vmcnt(0)" ::: "memory");
            __builtin_amdgcn_s_barrier();
            #pragma unroll
            for (int n = 0; n < 4; ++n) m2cur[n] = m2next[n];
        }
        cur ^= 1;
    }
#undef STAGE1

    // Epilogue: min across the 16 col-lanes, add f2, one atomic per row.
    #pragma unroll
    for (int mb = 0; mb < 4; ++mb)
        #pragma unroll
        for (int j = 0; j < 4; ++j) {
            float v = rmin[mb][j];
            v = fminf(v, __shfl_xor(v, 1));
            v = fminf(v, __shfl_xor(v, 2));
            v = fminf(v, __shfl_xor(v, 4));
            v = fminf(v, __shfl_xor(v, 8));
            if (c16 == 0) {
                int row = arow + mb * 16 + kq * 4 + j;
                if (row < N_FEAT)
                    atomicMin(nn + row, __float_as_uint(v + f2[row]));
            }
        }
}

// Merged finalize: blocks 0..UP_BLOCKS-1 do bilinear upsample; last NB blocks
// compute per-image max.
#define UP_BLOCKS ((NB * IMG * IMG) / 256)   // 1568
__global__ __launch_bounds__(256) void finalize_kernel(const unsigned int* __restrict__ nn,
                                                       float* __restrict__ out_scores,
                                                       float* __restrict__ out_up) {
    if (blockIdx.x >= UP_BLOCKS) {
        __shared__ float wmax[4];
        int b = blockIdx.x - UP_BLOCKS;
        int tid = threadIdx.x;
        float v = -INFINITY;
        for (int i = tid; i < PH * PW; i += 256)
            v = fmaxf(v, __uint_as_float(nn[b * PH * PW + i]));
        #pragma unroll
        for (int m = 1; m < 64; m <<= 1) v = fmaxf(v, __shfl_xor(v, m));
        if ((tid & 63) == 0) wmax[tid >> 6] = v;
        __syncthreads();
        if (tid == 0)
            out_scores[b] = fmaxf(fmaxf(wmax[0], wmax[1]), fmaxf(wmax[2], wmax[3]));
        return;
    }
    int idx = blockIdx.x * 256 + threadIdx.x;
    int b = idx / (IMG * IMG);
    int rem = idx - b * (IMG * IMG);
    int y = rem / IMG;
    int x = rem - y * IMG;
    float sy = y * 0.125f - 0.4375f;
    float sx = x * 0.125f - 0.4375f;
    float fy = floorf(sy), fx = floorf(sx);
    float ty = sy - fy, tx = sx - fx;
    int y0 = (int)fy, x0 = (int)fx;
    int y1 = min(y0 + 1, PH - 1), x1 = min(x0 + 1, PW - 1);
    y0 = max(y0, 0); x0 = max(x0, 0);
    const unsigned int* p = nn + b * PH * PW;
    float v00 = __uint_as_float(p[y0 * PW + x0]);
    float v01 = __uint_as_float(p[y0 * PW + x1]);
    float v10 = __uint_as_float(p[y1 * PW + x0]);
    float v11 = __uint_as_float(p[y1 * PW + x1]);
    float v0 = v00 + tx * (v01 - v00);
    float v1 = v10 + tx * (v11 - v10);
    out_up[idx] = v0 + ty * (v1 - v0);
}

extern "C" void kernel_launch(void* const* d_in, const int* in_sizes, int n_in,
                              void* d_out, int out_size, void* d_ws, size_t ws_size,
                              hipStream_t stream) {
    const float* feat = (const float*)d_in[0];   // [6272,128] f32
    const float* bank = (const float*)d_in[1];   // [30000,128] f32
    char* ws = (char*)d_ws;
    unsigned char* mbt = (unsigned char*)(ws + 0);     // 30080*128*2 = 7,700,480 (tiled)
    __bf16*        fbb = (__bf16*)(ws + 7700480);      // 6272*128*2  = 1,605,632
    float*         m2  = (float*)(ws + 9306112);       // 30080*4
    float*         f2  = (float*)(ws + 9426432);       // 6272*4
    unsigned int*  nn  = (unsigned int*)(ws + 9451520);// 6272*4
    float* out_scores = (float*)d_out;                 // [8]
    float* out_up     = out_scores + NB;               // [8,224,224]

    hipLaunchKernelGGL(prep_all, dim3(BANK_BLOCKS + FEAT_BLOCKS), dim3(256), 0, stream,
                       bank, feat, mbt, m2, fbb, f2, nn);
    hipLaunchKernelGGL(dist_min_kernel, dim3((N_FEAT + BM - 1) / BM, CHUNKS), dim3(256), 0,
                       stream, fbb, mbt, f2, m2, nn);
    hipLaunchKernelGGL(finalize_kernel, dim3(UP_BLOCKS + NB), dim3(256), 0, stream,
                       nn, out_scores, out_up);
}

// Round 12
// 55.650 us; speedup vs baseline: 1.2886x; 1.2886x over previous
//
#include <hip/hip_runtime.h>
#include <hip/hip_bf16.h>
#include <math.h>

#define N_FEAT 6272
#define DIM    128
#define M_BANK 30000
#define M_PAD  30080
#define NB     8
#define PH     28
#define PW     28
#define IMG    224
#define BM     256        // 4 waves x 64 rows (4 mb-blocks of 16)
#define BN     64         // bank cols per tile
#define TPT    10         // tiles per chunk: 470 / 47
#define CHUNKS 47
#define TILE_BYTES 8192   // 64 cols x 128 k x 1B (fp8)

#define BANKQ_BLOCKS (M_PAD / 64)    // 470
#define FEATQ_BLOCKS (N_FEAT / 64)   // 98

typedef __attribute__((ext_vector_type(4)))  int    i32x4;
typedef __attribute__((ext_vector_type(8)))  int    i32x8;
typedef __attribute__((ext_vector_type(4)))  float  f32x4;
typedef __attribute__((ext_vector_type(2)))  float  f32x2;

typedef const __attribute__((address_space(1))) unsigned int g_u32;
typedef __attribute__((address_space(3))) unsigned int l_u32;

// Quantize 32 floats -> 8 dwords of fp8 e4m3 (OCP, RNE, satfinite).
static __device__ __forceinline__ void q32(const float* x, i32x4& q0, i32x4& q1) {
    #pragma unroll
    for (int d = 0; d < 4; ++d) {
        int t = __builtin_amdgcn_cvt_pk_fp8_f32(x[d*4+0], x[d*4+1], 0, false);
        t     = __builtin_amdgcn_cvt_pk_fp8_f32(x[d*4+2], x[d*4+3], t, true);
        q0[d] = t;
    }
    #pragma unroll
    for (int d = 0; d < 4; ++d) {
        int t = __builtin_amdgcn_cvt_pk_fp8_f32(x[16+d*4+0], x[16+d*4+1], 0, false);
        t     = __builtin_amdgcn_cvt_pk_fp8_f32(x[16+d*4+2], x[16+d*4+3], t, true);
        q1[d] = t;
    }
}

// Fused prep. Bank blocks: fp8-quantize + retile into B-fragment order:
// tile t (64 cols) | kq-slice s (4 x 2KB) | half h (2 x 1KB, 16 k-elems) |
// col*16. The half-split makes ds_read_b128 bank-uniform (16 cols x 16B
// stride covers all 32 banks). Also biased m2 (+1024 keeps the selection
// metric positive for u64 packing; +inf for pad rows). Feature blocks:
// row-major fp8 + nn64 init.
__global__ __launch_bounds__(256) void prep_all(const float* __restrict__ bank,
                                                const float* __restrict__ feat,
                                                unsigned char* __restrict__ mbq,
                                                unsigned char* __restrict__ fbq,
                                                float* __restrict__ m2b,
                                                unsigned long long* __restrict__ nn64) {
    const int tid = threadIdx.x;
    const int c   = tid >> 2;     // row within 64-row block
    const int s   = tid & 3;      // 32-elem k slice
    float x[32];
    if (blockIdx.x < BANKQ_BLOCKS) {
        const int r = blockIdx.x * 64 + c;
        const bool valid = r < M_BANK;
        if (valid) {
            #pragma unroll
            for (int i = 0; i < 8; ++i) {
                f32x4 v = *(const f32x4*)(bank + (size_t)r * DIM + s * 32 + i * 4);
                x[i*4+0]=v.x; x[i*4+1]=v.y; x[i*4+2]=v.z; x[i*4+3]=v.w;
            }
        } else {
            #pragma unroll
            for (int i = 0; i < 32; ++i) x[i] = 0.f;
        }
        float sum = 0.f;
        #pragma unroll
        for (int i = 0; i < 32; ++i) sum += x[i] * x[i];
        sum += __shfl_xor(sum, 1);
        sum += __shfl_xor(sum, 2);
        i32x4 q0, q1;
        q32(x, q0, q1);
        unsigned char* base = mbq + (size_t)(r >> 6) * TILE_BYTES + s * 2048 + (r & 63) * 16;
        *(i32x4*)(base)        = q0;   // k elems 0-15 of slice
        *(i32x4*)(base + 1024) = q1;   // k elems 16-31
        if (s == 0) m2b[r] = valid ? (sum + 1024.0f) : INFINITY;
        return;
    }
    const int r = (blockIdx.x - BANKQ_BLOCKS) * 64 + c;   // exact: 98*64 = 6272
    #pragma unroll
    for (int i = 0; i < 8; ++i) {
        f32x4 v = *(const f32x4*)(feat + (size_t)r * DIM + s * 32 + i * 4);
        x[i*4+0]=v.x; x[i*4+1]=v.y; x[i*4+2]=v.z; x[i*4+3]=v.w;
    }
    i32x4 q0, q1;
    q32(x, q0, q1);
    *(i32x4*)(fbq + (size_t)r * DIM + s * 32)      = q0;
    *(i32x4*)(fbq + (size_t)r * DIM + s * 32 + 16) = q1;
    if (s == 0) nn64[r] = 0xFFFFFFFFFFFFFFFFull;
}

// fp8 K=128 argmin kernel: 4 waves x 64 rows (4 mb x 16), one
// mfma_scale_f32_16x16x128_f8f6f4 (unit scales) per (mb, 16-col group) --
// no kk chain. Selection metric m2b - 2*f8dot (f2 constant per row ->
// irrelevant to argmin). Tracks (minval, colidx); publishes packed u64
// atomicMin. Exact distance recomputed later by rescue_kernel in fp32.
__global__ __launch_bounds__(256, 3) void dist_min_kernel(
        const unsigned char* __restrict__ fbq, const unsigned char* __restrict__ mbq,
        const float* __restrict__ m2b, unsigned long long* __restrict__ nn64) {
    __shared__ __align__(16) unsigned char lds[2 * TILE_BYTES];
    const int tid  = threadIdx.x;
    const int lane = tid & 63;
    const int w    = tid >> 6;
    const int c16  = lane & 15;   // A-row16 / B-col16 / C-col
    const int kq   = lane >> 4;   // k-quarter (32 elems each)
    const int arow = blockIdx.x * BM + w * 64;
    const int tile0 = blockIdx.y * TPT;

    // A fragments: afrag[mb] = A[arow+mb*16+c16][kq*32 .. +31] (8 dwords fp8)
    i32x8 afrag[4];
    #pragma unroll
    for (int mb = 0; mb < 4; ++mb) {
        int row = arow + mb * 16 + c16;
        if (row >= N_FEAT) row = N_FEAT - 1;   // tail clamp (discarded)
        i32x4 lo = *(const i32x4*)(fbq + (size_t)row * DIM + kq * 32);
        i32x4 hi = *(const i32x4*)(fbq + (size_t)row * DIM + kq * 32 + 16);
        afrag[mb] = __builtin_shufflevector(lo, hi, 0, 1, 2, 3, 4, 5, 6, 7);
    }

    float        minv[4][4];
    unsigned int mini[4][4];
    #pragma unroll
    for (int mb = 0; mb < 4; ++mb)
        #pragma unroll
        for (int j = 0; j < 4; ++j) { minv[mb][j] = INFINITY; mini[mb][j] = 0u; }

#define STAGE(tile_idx, bufsel)                                                      \
    {   const unsigned char* sp_ = mbq + (size_t)(tile_idx) * TILE_BYTES + tid * 16; \
        unsigned char* dp_ = lds + (bufsel) * TILE_BYTES + tid * 16;                 \
        __builtin_amdgcn_global_load_lds((g_u32*)(sp_),        (l_u32*)(dp_), 16, 0, 0);          \
        __builtin_amdgcn_global_load_lds((g_u32*)(sp_ + 4096), (l_u32*)(dp_ + 4096), 16, 0, 0); }

    // prologue: m2b for tile0 (before STAGE: vmcnt-FIFO discipline), stage.
    float m2c[4];
    #pragma unroll
    for (int n = 0; n < 4; ++n) m2c[n] = m2b[tile0 * BN + n * 16 + c16];
    STAGE(tile0, 0);
    __syncthreads();

    const f32x4 zacc = {0.f, 0.f, 0.f, 0.f};
    int cur = 0;
    #pragma unroll 1
    for (int t = 0; t < TPT; ++t) {
        float m2n[4];
        if (t + 1 < TPT) {
            #pragma unroll
            for (int n = 0; n < 4; ++n)
                m2n[n] = m2b[(tile0 + t + 1) * BN + n * 16 + c16];
            STAGE(tile0 + t + 1, cur ^ 1);
        }
        const unsigned char* buf = lds + cur * TILE_BYTES;
        #pragma unroll
        for (int n = 0; n < 4; ++n) {
            const int col = n * 16 + c16;
            i32x4 b0 = *(const i32x4*)(buf + kq * 2048 + col * 16);
            i32x4 b1 = *(const i32x4*)(buf + kq * 2048 + 1024 + col * 16);
            i32x8 bfrag = __builtin_shufflevector(b0, b1, 0, 1, 2, 3, 4, 5, 6, 7);
            const unsigned int colidx = (unsigned int)(tile0 + t) * BN + col;
            #pragma unroll
            for (int mb = 0; mb < 4; ++mb) {
                f32x4 acc = __builtin_amdgcn_mfma_scale_f32_16x16x128_f8f6f4(
                    afrag[mb], bfrag, zacc, 0, 0, 0, 127, 0, 127);
                #pragma unroll
                for (int j = 0; j < 4; ++j) {
                    float d = fmaf(-2.f, acc[j], m2c[n]);
                    bool lt = d < minv[mb][j];
                    minv[mb][j] = lt ? d : minv[mb][j];
                    mini[mb][j] = lt ? colidx : mini[mb][j];
                }
            }
        }
        __syncthreads();
        if (t + 1 < TPT) {
            #pragma unroll
            for (int n = 0; n < 4; ++n) m2c[n] = m2n[n];
        }
        cur ^= 1;
    }
#undef STAGE

    // Epilogue: argmin across the 16 col-lanes (same kq), one u64 atomic/row.
    #pragma unroll
    for (int mb = 0; mb < 4; ++mb)
        #pragma unroll
        for (int j = 0; j < 4; ++j) {
            float v = minv[mb][j];
            unsigned int ii = mini[mb][j];
            #pragma unroll
            for (int k = 1; k < 16; k <<= 1) {
                float sv = __shfl_xor(v, k);
                unsigned int si = __shfl_xor(ii, k);
                if (sv < v) { v = sv; ii = si; }
            }
            if (c16 == 0) {
                int row = arow + mb * 16 + kq * 4 + j;
                if (row < N_FEAT) {
                    unsigned long long pack =
                        ((unsigned long long)__float_as_uint(v) << 32) | ii;
                    atomicMin(nn64 + row, pack);
                }
            }
        }
}

// Exact fp32 distance for the selected neighbor: one wave per row.
__global__ __launch_bounds__(256) void rescue_kernel(const float* __restrict__ feat,
                                                     const float* __restrict__ bank,
                                                     const unsigned long long* __restrict__ nn64,
                                                     float* __restrict__ nnf) {
    const int row  = blockIdx.x * 4 + (threadIdx.x >> 6);   // 1568*4 = 6272 exact
    const int lane = threadIdx.x & 63;
    const unsigned int idx = (unsigned int)(nn64[row] & 0xFFFFFFFFull);
    f32x2 f = *(const f32x2*)(feat + (size_t)row * DIM + lane * 2);
    f32x2 m = *(const f32x2*)(bank + (size_t)idx * DIM + lane * 2);
    float dx = f.x - m.x, dy = f.y - m.y;
    float d = dx * dx + dy * dy;
    #pragma unroll
    for (int k = 1; k < 64; k <<= 1) d += __shfl_xor(d, k);
    if (lane == 0) nnf[row] = d;
}

// Merged finalize: blocks 0..UP_BLOCKS-1 bilinear upsample; last NB blocks
// per-image max.
#define UP_BLOCKS ((NB * IMG * IMG) / 256)   // 1568
__global__ __launch_bounds__(256) void finalize_kernel(const float* __restrict__ nnf,
                                                       float* __restrict__ out_scores,
                                                       float* __restrict__ out_up) {
    if (blockIdx.x >= UP_BLOCKS) {
        __shared__ float wmax[4];
        int b = blockIdx.x - UP_BLOCKS;
        int tid = threadIdx.x;
        float v = -INFINITY;
        for (int i = tid; i < PH * PW; i += 256)
            v = fmaxf(v, nnf[b * PH * PW + i]);
        #pragma unroll
        for (int m = 1; m < 64; m <<= 1) v = fmaxf(v, __shfl_xor(v, m));
        if ((tid & 63) == 0) wmax[tid >> 6] = v;
        __syncthreads();
        if (tid == 0)
            out_scores[b] = fmaxf(fmaxf(wmax[0], wmax[1]), fmaxf(wmax[2], wmax[3]));
        return;
    }
    int idx = blockIdx.x * 256 + threadIdx.x;
    int b = idx / (IMG * IMG);
    int rem = idx - b * (IMG * IMG);
    int y = rem / IMG;
    int x = rem - y * IMG;
    float sy = y * 0.125f - 0.4375f;
    float sx = x * 0.125f - 0.4375f;
    float fy = floorf(sy), fx = floorf(sx);
    float ty = sy - fy, tx = sx - fx;
    int y0 = (int)fy, x0 = (int)fx;
    int y1 = min(y0 + 1, PH - 1), x1 = min(x0 + 1, PW - 1);
    y0 = max(y0, 0); x0 = max(x0, 0);
    const float* p = nnf + b * PH * PW;
    float v00 = p[y0 * PW + x0];
    float v01 = p[y0 * PW + x1];
    float v10 = p[y1 * PW + x0];
    float v11 = p[y1 * PW + x1];
    float v0 = v00 + tx * (v01 - v00);
    float v1 = v10 + tx * (v11 - v10);
    out_up[idx] = v0 + ty * (v1 - v0);
}

extern "C" void kernel_launch(void* const* d_in, const int* in_sizes, int n_in,
                              void* d_out, int out_size, void* d_ws, size_t ws_size,
                              hipStream_t stream) {
    const float* feat = (const float*)d_in[0];   // [6272,128] f32
    const float* bank = (const float*)d_in[1];   // [30000,128] f32
    char* ws = (char*)d_ws;
    unsigned char*      mbq  = (unsigned char*)(ws + 0);        // 30080*128 fp8 tiled = 3,850,240
    unsigned char*      fbq  = (unsigned char*)(ws + 3850240);  // 6272*128 fp8 = 802,816
    float*              m2b  = (float*)(ws + 4653056);          // 30080*4 (biased +1024)
    unsigned long long* nn64 = (unsigned long long*)(ws + 4773376); // 6272*8
    float*              nnf  = (float*)(ws + 4823552);          // 6272*4
    float* out_scores = (float*)d_out;                          // [8]
    float* out_up     = out_scores + NB;                        // [8,224,224]

    hipLaunchKernelGGL(prep_all, dim3(BANKQ_BLOCKS + FEATQ_BLOCKS), dim3(256), 0, stream,
                       bank, feat, mbq, fbq, m2b, nn64);
    hipLaunchKernelGGL(dist_min_kernel, dim3((N_FEAT + BM - 1) / BM, CHUNKS), dim3(256), 0,
                       stream, fbq, mbq, m2b, nn64);
    hipLaunchKernelGGL(rescue_kernel, dim3(N_FEAT / 4), dim3(256), 0, stream,
                       feat, bank, nn64, nnf);
    hipLaunchKernelGGL(finalize_kernel, dim3(UP_BLOCKS + NB), dim3(256), 0, stream,
                       nnf, out_scores, out_up);
}

// Round 13
// 54.244 us; speedup vs baseline: 1.3220x; 1.0259x over previous
//
#include <hip/hip_runtime.h>
#include <hip/hip_bf16.h>
#include <math.h>

#define N_FEAT 6272
#define DIM    128
#define M_BANK 30000
#define M_PAD  30080
#define NB     8
#define PH     28
#define PW     28
#define IMG    224
#define BM     256        // 4 waves x 64 rows (4 mb-blocks of 16)
#define BN     64         // bank cols per tile
#define TPT    10         // tiles per chunk: 470 / 47
#define CHUNKS 47
#define TILE_BYTES 8192   // 64 cols x 128 k x 1B (fp8)

#define BANKQ_BLOCKS (M_PAD / 64)    // 470
#define FEATQ_BLOCKS (N_FEAT / 64)   // 98

typedef __attribute__((ext_vector_type(4)))  int    i32x4;
typedef __attribute__((ext_vector_type(8)))  int    i32x8;
typedef __attribute__((ext_vector_type(4)))  float  f32x4;
typedef __attribute__((ext_vector_type(2)))  float  f32x2;

typedef const __attribute__((address_space(1))) unsigned int g_u32;
typedef __attribute__((address_space(3))) unsigned int l_u32;

// Quantize 32 floats -> 8 dwords of fp8 e4m3 (OCP, RNE, satfinite).
static __device__ __forceinline__ void q32(const float* x, i32x4& q0, i32x4& q1) {
    #pragma unroll
    for (int d = 0; d < 4; ++d) {
        int t = __builtin_amdgcn_cvt_pk_fp8_f32(x[d*4+0], x[d*4+1], 0, false);
        t     = __builtin_amdgcn_cvt_pk_fp8_f32(x[d*4+2], x[d*4+3], t, true);
        q0[d] = t;
    }
    #pragma unroll
    for (int d = 0; d < 4; ++d) {
        int t = __builtin_amdgcn_cvt_pk_fp8_f32(x[16+d*4+0], x[16+d*4+1], 0, false);
        t     = __builtin_amdgcn_cvt_pk_fp8_f32(x[16+d*4+2], x[16+d*4+3], t, true);
        q1[d] = t;
    }
}

// Fused prep. Bank blocks: fp8-quantize + retile into B-fragment order:
// tile t (64 cols) | kq-slice s (4 x 2KB) | half (2 x 1KB) | col*16.
// Stores m2h = -(|m|^2 + 1024)/2 (MFMA C operand; -inf for pad rows, so pad
// cols never win the max). Feature blocks: row-major fp8 + nn64 init.
__global__ __launch_bounds__(256) void prep_all(const float* __restrict__ bank,
                                                const float* __restrict__ feat,
                                                unsigned char* __restrict__ mbq,
                                                unsigned char* __restrict__ fbq,
                                                float* __restrict__ m2h,
                                                unsigned long long* __restrict__ nn64) {
    const int tid = threadIdx.x;
    const int c   = tid >> 2;     // row within 64-row block
    const int s   = tid & 3;      // 32-elem k slice
    float x[32];
    if (blockIdx.x < BANKQ_BLOCKS) {
        const int r = blockIdx.x * 64 + c;
        const bool valid = r < M_BANK;
        if (valid) {
            #pragma unroll
            for (int i = 0; i < 8; ++i) {
                f32x4 v = *(const f32x4*)(bank + (size_t)r * DIM + s * 32 + i * 4);
                x[i*4+0]=v.x; x[i*4+1]=v.y; x[i*4+2]=v.z; x[i*4+3]=v.w;
            }
        } else {
            #pragma unroll
            for (int i = 0; i < 32; ++i) x[i] = 0.f;
        }
        float sum = 0.f;
        #pragma unroll
        for (int i = 0; i < 32; ++i) sum += x[i] * x[i];
        sum += __shfl_xor(sum, 1);
        sum += __shfl_xor(sum, 2);
        i32x4 q0, q1;
        q32(x, q0, q1);
        unsigned char* base = mbq + (size_t)(r >> 6) * TILE_BYTES + s * 2048 + (r & 63) * 16;
        *(i32x4*)(base)        = q0;   // k elems 0-15 of slice
        *(i32x4*)(base + 1024) = q1;   // k elems 16-31
        if (s == 0) m2h[r] = valid ? (-0.5f * (sum + 1024.0f)) : -INFINITY;
        return;
    }
    const int r = (blockIdx.x - BANKQ_BLOCKS) * 64 + c;   // exact: 98*64 = 6272
    #pragma unroll
    for (int i = 0; i < 8; ++i) {
        f32x4 v = *(const f32x4*)(feat + (size_t)r * DIM + s * 32 + i * 4);
        x[i*4+0]=v.x; x[i*4+1]=v.y; x[i*4+2]=v.z; x[i*4+3]=v.w;
    }
    i32x4 q0, q1;
    q32(x, q0, q1);
    *(i32x4*)(fbq + (size_t)r * DIM + s * 32)      = q0;
    *(i32x4*)(fbq + (size_t)r * DIM + s * 32 + 16) = q1;
    if (s == 0) nn64[r] = 0xFFFFFFFFFFFFFFFFull;
}

// fp8 K=128 argmin with MFMA C-folding: C = m2h[col] broadcast, so
// acc = dot - (|m|^2+1024)/2 and min-distance == MAX-acc. Fold is
// cmp_gt + 2 cndmask = 3 VALU/pair (no fma). Epilogue: argmax across the
// 16 col-lanes, pack bits(-maxv) (positive, monotone) | colidx into u64
// atomicMin. Exact distance recomputed by rescue_kernel.
__global__ __launch_bounds__(256, 4) void dist_min_kernel(
        const unsigned char* __restrict__ fbq, const unsigned char* __restrict__ mbq,
        const float* __restrict__ m2h, unsigned long long* __restrict__ nn64) {
    __shared__ __align__(16) unsigned char lds[2 * TILE_BYTES];
    const int tid  = threadIdx.x;
    const int lane = tid & 63;
    const int w    = tid >> 6;
    const int c16  = lane & 15;   // A-row16 / B-col16 / C-col
    const int kq   = lane >> 4;   // k-quarter (32 elems each)
    const int arow = blockIdx.x * BM + w * 64;
    const int tile0 = blockIdx.y * TPT;

    // A fragments: afrag[mb] = A[arow+mb*16+c16][kq*32 .. +31] (8 dwords fp8)
    i32x8 afrag[4];
    #pragma unroll
    for (int mb = 0; mb < 4; ++mb) {
        int row = arow + mb * 16 + c16;
        if (row >= N_FEAT) row = N_FEAT - 1;   // tail clamp (discarded)
        i32x4 lo = *(const i32x4*)(fbq + (size_t)row * DIM + kq * 32);
        i32x4 hi = *(const i32x4*)(fbq + (size_t)row * DIM + kq * 32 + 16);
        afrag[mb] = __builtin_shufflevector(lo, hi, 0, 1, 2, 3, 4, 5, 6, 7);
    }

    float        maxv[4][4];
    unsigned int mini[4][4];
    #pragma unroll
    for (int mb = 0; mb < 4; ++mb)
        #pragma unroll
        for (int j = 0; j < 4; ++j) { maxv[mb][j] = -INFINITY; mini[mb][j] = 0u; }

#define STAGE(tile_idx, bufsel)                                                      \
    {   const unsigned char* sp_ = mbq + (size_t)(tile_idx) * TILE_BYTES + tid * 16; \
        unsigned char* dp_ = lds + (bufsel) * TILE_BYTES + tid * 16;                 \
        __builtin_amdgcn_global_load_lds((g_u32*)(sp_),        (l_u32*)(dp_), 16, 0, 0);          \
        __builtin_amdgcn_global_load_lds((g_u32*)(sp_ + 4096), (l_u32*)(dp_ + 4096), 16, 0, 0); }

    // prologue: m2h for tile0 (before STAGE: vmcnt-FIFO discipline), stage.
    float m2c[4];
    #pragma unroll
    for (int n = 0; n < 4; ++n) m2c[n] = m2h[tile0 * BN + n * 16 + c16];
    STAGE(tile0, 0);
    __syncthreads();

    int cur = 0;
    #pragma unroll 1
    for (int t = 0; t < TPT; ++t) {
        float m2n[4];
        if (t + 1 < TPT) {
            #pragma unroll
            for (int n = 0; n < 4; ++n)
                m2n[n] = m2h[(tile0 + t + 1) * BN + n * 16 + c16];
            STAGE(tile0 + t + 1, cur ^ 1);
        }
        const unsigned char* buf = lds + cur * TILE_BYTES;
        const unsigned int tbase = (unsigned int)(tile0 + t) * BN + c16;
        #pragma unroll
        for (int n = 0; n < 4; ++n) {
            const int col = n * 16 + c16;
            i32x4 b0 = *(const i32x4*)(buf + kq * 2048 + col * 16);
            i32x4 b1 = *(const i32x4*)(buf + kq * 2048 + 1024 + col * 16);
            i32x8 bfrag = __builtin_shufflevector(b0, b1, 0, 1, 2, 3, 4, 5, 6, 7);
            const f32x4 cin = {m2c[n], m2c[n], m2c[n], m2c[n]};
            const unsigned int colidx = tbase + n * 16;
            #pragma unroll
            for (int mb = 0; mb < 4; ++mb) {
                f32x4 acc = __builtin_amdgcn_mfma_scale_f32_16x16x128_f8f6f4(
                    afrag[mb], bfrag, cin, 0, 0, 0, 127, 0, 127);
                #pragma unroll
                for (int j = 0; j < 4; ++j) {
                    bool gt = acc[j] > maxv[mb][j];
                    maxv[mb][j] = gt ? acc[j] : maxv[mb][j];
                    mini[mb][j] = gt ? colidx : mini[mb][j];
                }
            }
        }
        __syncthreads();
        if (t + 1 < TPT) {
            #pragma unroll
            for (int n = 0; n < 4; ++n) m2c[n] = m2n[n];
        }
        cur ^= 1;
    }
#undef STAGE

    // Epilogue: argmax across the 16 col-lanes (same kq), one u64 atomic/row.
    #pragma unroll
    for (int mb = 0; mb < 4; ++mb)
        #pragma unroll
        for (int j = 0; j < 4; ++j) {
            float v = maxv[mb][j];
            unsigned int ii = mini[mb][j];
            #pragma unroll
            for (int k = 1; k < 16; k <<= 1) {
                float sv = __shfl_xor(v, k);
                unsigned int si = __shfl_xor(ii, k);
                if (sv > v) { v = sv; ii = si; }
            }
            if (c16 == 0) {
                int row = arow + mb * 16 + kq * 4 + j;
                if (row < N_FEAT) {
                    // -v = (|m|^2+1024)/2 - dot > 0: positive float, monotone
                    // in distance -> u64 atomicMin selects the true argmax.
                    unsigned long long pack =
                        ((unsigned long long)__float_as_uint(-v) << 32) | ii;
                    atomicMin(nn64 + row, pack);
                }
            }
        }
}

// Exact fp32 distance for the selected neighbor: one wave per row.
__global__ __launch_bounds__(256) void rescue_kernel(const float* __restrict__ feat,
                                                     const float* __restrict__ bank,
                                                     const unsigned long long* __restrict__ nn64,
                                                     float* __restrict__ nnf) {
    const int row  = blockIdx.x * 4 + (threadIdx.x >> 6);   // 1568*4 = 6272 exact
    const int lane = threadIdx.x & 63;
    const unsigned int idx = (unsigned int)(nn64[row] & 0xFFFFFFFFull);
    f32x2 f = *(const f32x2*)(feat + (size_t)row * DIM + lane * 2);
    f32x2 m = *(const f32x2*)(bank + (size_t)idx * DIM + lane * 2);
    float dx = f.x - m.x, dy = f.y - m.y;
    float d = dx * dx + dy * dy;
    #pragma unroll
    for (int k = 1; k < 64; k <<= 1) d += __shfl_xor(d, k);
    if (lane == 0) nnf[row] = d;
}

// Merged finalize: blocks 0..UP_BLOCKS-1 bilinear upsample; last NB blocks
// per-image max.
#define UP_BLOCKS ((NB * IMG * IMG) / 256)   // 1568
__global__ __launch_bounds__(256) void finalize_kernel(const float* __restrict__ nnf,
                                                       float* __restrict__ out_scores,
                                                       float* __restrict__ out_up) {
    if (blockIdx.x >= UP_BLOCKS) {
        __shared__ float wmax[4];
        int b = blockIdx.x - UP_BLOCKS;
        int tid = threadIdx.x;
        float v = -INFINITY;
        for (int i = tid; i < PH * PW; i += 256)
            v = fmaxf(v, nnf[b * PH * PW + i]);
        #pragma unroll
        for (int m = 1; m < 64; m <<= 1) v = fmaxf(v, __shfl_xor(v, m));
        if ((tid & 63) == 0) wmax[tid >> 6] = v;
        __syncthreads();
        if (tid == 0)
            out_scores[b] = fmaxf(fmaxf(wmax[0], wmax[1]), fmaxf(wmax[2], wmax[3]));
        return;
    }
    int idx = blockIdx.x * 256 + threadIdx.x;
    int b = idx / (IMG * IMG);
    int rem = idx - b * (IMG * IMG);
    int y = rem / IMG;
    int x = rem - y * IMG;
    float sy = y * 0.125f - 0.4375f;
    float sx = x * 0.125f - 0.4375f;
    float fy = floorf(sy), fx = floorf(sx);
    float ty = sy - fy, tx = sx - fx;
    int y0 = (int)fy, x0 = (int)fx;
    int y1 = min(y0 + 1, PH - 1), x1 = min(x0 + 1, PW - 1);
    y0 = max(y0, 0); x0 = max(x0, 0);
    const float* p = nnf + b * PH * PW;
    float v00 = p[y0 * PW + x0];
    float v01 = p[y0 * PW + x1];
    float v10 = p[y1 * PW + x0];
    float v11 = p[y1 * PW + x1];
    float v0 = v00 + tx * (v01 - v00);
    float v1 = v10 + tx * (v11 - v10);
    out_up[idx] = v0 + ty * (v1 - v0);
}

extern "C" void kernel_launch(void* const* d_in, const int* in_sizes, int n_in,
                              void* d_out, int out_size, void* d_ws, size_t ws_size,
                              hipStream_t stream) {
    const float* feat = (const float*)d_in[0];   // [6272,128] f32
    const float* bank = (const float*)d_in[1];   // [30000,128] f32
    char* ws = (char*)d_ws;
    unsigned char*      mbq  = (unsigned char*)(ws + 0);        // 30080*128 fp8 tiled = 3,850,240
    unsigned char*      fbq  = (unsigned char*)(ws + 3850240);  // 6272*128 fp8 = 802,816
    float*              m2h  = (float*)(ws + 4653056);          // 30080*4 (= -(m2+1024)/2)
    unsigned long long* nn64 = (unsigned long long*)(ws + 4773376); // 6272*8
    float*              nnf  = (float*)(ws + 4823552);          // 6272*4
    float* out_scores = (float*)d_out;                          // [8]
    float* out_up     = out_scores + NB;                        // [8,224,224]

    hipLaunchKernelGGL(prep_all, dim3(BANKQ_BLOCKS + FEATQ_BLOCKS), dim3(256), 0, stream,
                       bank, feat, mbq, fbq, m2h, nn64);
    hipLaunchKernelGGL(dist_min_kernel, dim3((N_FEAT + BM - 1) / BM, CHUNKS), dim3(256), 0,
                       stream, fbq, mbq, m2h, nn64);
    hipLaunchKernelGGL(rescue_kernel, dim3(N_FEAT / 4), dim3(256), 0, stream,
                       feat, bank, nn64, nnf);
    hipLaunchKernelGGL(finalize_kernel, dim3(UP_BLOCKS + NB), dim3(256), 0, stream,
                       nnf, out_scores, out_up);
}